// Round 4
// baseline (712.475 us; speedup 1.0000x reference)
//
#include <hip/hip_runtime.h>
#include <math.h>

#define BB 32
#define CC 256
#define LL 4096

typedef __attribute__((ext_vector_type(8))) short bf16x8;
typedef __attribute__((ext_vector_type(4))) float f32x4;

__device__ __forceinline__ unsigned short f2bf(float f) {
  unsigned u = __float_as_uint(f);
  u = (u + 0x7FFFu + ((u >> 16) & 1u)) >> 16;
  return (unsigned short)u;
}
__device__ __forceinline__ float bf2f(unsigned short v) {
  return __uint_as_float(((unsigned)v) << 16);
}
// XOR-swizzle of a 16B-block index within a 1KB chunk (applied on both store & load)
__device__ __forceinline__ int swz16(int blk) { return blk ^ ((blk >> 3) & 7); }

// ---------------- init: biases (BN folded) ----------------
__global__ void init_bias(const float* __restrict__ g1, const float* __restrict__ b1,
                          const float* __restrict__ m1, const float* __restrict__ v1,
                          const float* __restrict__ g2, const float* __restrict__ b2,
                          const float* __restrict__ m2, const float* __restrict__ v2,
                          float* __restrict__ b1f, float* __restrict__ b2f) {
  int c = threadIdx.x;
  b1f[c] = b1[c] - m1[c] * g1[c] * rsqrtf(v1[c] + 1e-5f);
  b2f[c] = b2[c] - m2[c] * g2[c] * rsqrtf(v2[c] + 1e-5f);
}

// ---------------- init: conv weights, B-frag-linear bf16, BN-folded ----------------
__global__ void init_wsw(const float* __restrict__ w1, const float* __restrict__ g1,
                         const float* __restrict__ v1,
                         const float* __restrict__ w2, const float* __restrict__ g2,
                         const float* __restrict__ v2,
                         unsigned short* __restrict__ W1sw, unsigned short* __restrict__ W2sw) {
  int id = blockIdx.x * 256 + threadIdx.x; // 393216
  int cv = id / 196608;
  int i = id - cv * 196608;
  int kc3t = i >> 13;
  int kc = kc3t / 3, t = kc3t - 3 * kc;
  int rem = i & 8191;
  int nt = rem >> 9, L = (rem >> 3) & 63, j = i & 7;
  int co = nt * 16 + (L & 15);
  int ci = kc * 32 + ((L >> 4) << 3) + j;
  if (cv == 0) {
    float s = g1[co] * rsqrtf(v1[co] + 1e-5f);
    W1sw[i] = f2bf(w1[(co * 256 + ci) * 3 + t] * s);
  } else {
    float s = g2[co] * rsqrtf(v2[co] + 1e-5f);
    W2sw[i] = f2bf(w2[(co * 256 + ci) * 3 + t] * s);
  }
}

// ---------------- init: GEMM-chain B matrices, frag-linear bf16 ----------------
__global__ void init_bsw(const float* __restrict__ fc1, const float* __restrict__ fc2,
                         unsigned short* __restrict__ Bd, unsigned short* __restrict__ B1,
                         unsigned short* __restrict__ B2) {
  int id = blockIdx.x * 256 + threadIdx.x; // 327680 total
  if (id < 65536) {
    int i = id;
    int kc = i >> 13, nt = (i >> 9) & 15, L = (i >> 3) & 63, j = i & 7;
    int n = nt * 16 + (L & 15), k = kc * 32 + (L >> 4) * 8 + j;
    // exact integer phase reduction mod 1024, then single-precision cos
    int m = (n * (2 * k + 1)) & 1023;
    float v = 2.0f * cosf(3.14159265358979323846f * (float)m * (1.0f / 512.0f));
    Bd[i] = f2bf(v);
  } else if (id < 65536 + 131072) {
    int i = id - 65536;
    int kc = i >> 14, nt = (i >> 9) & 31, L = (i >> 3) & 63, j = i & 7;
    int n = nt * 16 + (L & 15), k = kc * 32 + (L >> 4) * 8 + j;
    B1[i] = f2bf(fc1[n * 256 + k]);
  } else {
    int i = id - 65536 - 131072;
    int kc = i >> 13, nt = (i >> 9) & 15, L = (i >> 3) & 63, j = i & 7;
    int n = nt * 16 + (L & 15), k = kc * 32 + (L >> 4) * 8 + j;
    B2[i] = f2bf(fc2[n * 512 + k]);
  }
}

// ---------------- transpose: x fp32 [b][ci][l] -> xT bf16 [b][l][ci] ----------------
__global__ __launch_bounds__(256) void transpose_x(const float* __restrict__ x,
                                                   unsigned short* __restrict__ xT) {
  __shared__ unsigned short ts[64][68];
  const int tid = threadIdx.x;
  const int b = blockIdx.z, ci0 = blockIdx.y << 6, l0 = blockIdx.x << 6;
#pragma unroll
  for (int p = 0; p < 4; ++p) {
    int cc = (p << 4) + (tid >> 4);
    int ll = (tid & 15) << 2;
    float4 v = *(const float4*)&x[((((size_t)b << 8) + ci0 + cc) << 12) + l0 + ll];
    ts[ll + 0][cc] = f2bf(v.x);
    ts[ll + 1][cc] = f2bf(v.y);
    ts[ll + 2][cc] = f2bf(v.z);
    ts[ll + 3][cc] = f2bf(v.w);
  }
  __syncthreads();
#pragma unroll
  for (int p = 0; p < 4; ++p) {
    int idx = tid + (p << 8);
    int row = idx >> 4, ch = idx & 15;
    uint2 v = *(const uint2*)&ts[row][ch << 2];
    *(uint2*)&xT[((((size_t)b << 12) + l0 + row) << 8) + ci0 + (ch << 2)] = v;
  }
}

// ---------------- conv as implicit GEMM (MFMA bf16 16x16x32) ----------------
// block: 64 l x 256 co, one b. K = (8 ci-chunks) x (3 taps).
// Barrier-free K-loop: B-fragments read per-lane directly from L2-resident Wsw
// (384 KB), xs read-only in LDS. 34.8 KB LDS -> 4 blocks/CU.
template <bool RELU, bool FRAGOUT>
__global__ __launch_bounds__(256, 3) void conv_mfma(
    const unsigned short* __restrict__ inT, const unsigned short* __restrict__ Wsw,
    const float* __restrict__ bias, unsigned short* __restrict__ outT) {
  __shared__ char smem[34848];
  unsigned short* xs = (unsigned short*)smem;  // [66][264]
  unsigned short* swz = (unsigned short*)smem; // epilogue alias [64][264]

  const int tid = threadIdx.x;
  const int w = tid >> 6, lane = tid & 63;
  const int g = lane >> 4, c = lane & 15;
  const int l0 = blockIdx.x << 6;
  const int b = blockIdx.y;
  const size_t rowbase = ((size_t)b << 12) + l0;

  // stage xs: rows l0-1 .. l0+64 (66), 256 ci each
  for (int idx = tid; idx < 66 * 32; idx += 256) {
    int r = idx >> 5, ch = idx & 31;
    int gl = l0 - 1 + r;
    uint4 v = {0, 0, 0, 0};
    if (gl >= 0 && gl < LL)
      v = *(const uint4*)&inT[((((size_t)b << 12) + gl) << 8) + (ch << 3)];
    *(uint4*)&xs[r * 264 + (ch << 3)] = v;
  }
  __syncthreads();

  f32x4 acc[4][4];
#pragma unroll
  for (int i = 0; i < 4; ++i)
#pragma unroll
    for (int j = 0; j < 4; ++j) acc[i][j] = (f32x4){0.f, 0.f, 0.f, 0.f};

  for (int kc = 0; kc < 8; ++kc)
#pragma unroll
    for (int t = 0; t < 3; ++t) {
      const unsigned short* src = Wsw + ((kc * 3 + t) << 13);
      bf16x8 af[4];
#pragma unroll
      for (int mt = 0; mt < 4; ++mt)
        af[mt] = *(const bf16x8*)&xs[(mt * 16 + c + t) * 264 + (kc << 5) + (g << 3)];
#pragma unroll
      for (int nt = 0; nt < 4; ++nt) {
        bf16x8 bfv = *(const bf16x8*)&src[(((w << 2) + nt) << 9) + (lane << 3)];
#pragma unroll
        for (int mt = 0; mt < 4; ++mt)
          acc[mt][nt] = __builtin_amdgcn_mfma_f32_16x16x32_bf16(af[mt], bfv, acc[mt][nt], 0, 0, 0);
      }
    }
  __syncthreads();

  float pb[4];
#pragma unroll
  for (int nt = 0; nt < 4; ++nt) pb[nt] = bias[(w << 6) + nt * 16 + c];
#pragma unroll
  for (int mt = 0; mt < 4; ++mt)
#pragma unroll
    for (int r = 0; r < 4; ++r) {
      int row = mt * 16 + g * 4 + r;
#pragma unroll
      for (int nt = 0; nt < 4; ++nt) {
        float v = acc[mt][nt][r] + pb[nt];
        if (RELU) v = fmaxf(v, 0.f);
        swz[row * 264 + (w << 6) + nt * 16 + c] = f2bf(v);
      }
    }
  __syncthreads();
  if (!FRAGOUT) {
#pragma unroll
    for (int i = 0; i < 8; ++i) {
      int idx = tid + (i << 8);
      int row = idx >> 5, ch = idx & 31;
      *(uint4*)&outT[((rowbase + row) << 8) + (ch << 3)] = *(const uint4*)&swz[row * 264 + (ch << 3)];
    }
  } else {
    const int MT0 = (int)(rowbase >> 4);
#pragma unroll
    for (int i = 0; i < 8; ++i) {
      int f = tid + (i << 8);
      int mtl = f >> 9, kcl = (f >> 6) & 7, L = f & 63;
      int row = mtl * 16 + (L & 15), k0 = (kcl << 5) + ((L >> 4) << 3);
      uint4 v = *(const uint4*)&swz[row * 264 + k0];
      *(uint4*)&outT[(((size_t)(MT0 + mtl) * 8 + kcl) << 9) + L * 8] = v;
    }
  }
}

// ---------------- FULLY FUSED GEMM chain ----------------
// LDS 40960 B; launch_bounds (256,3) so the allocator stays ~80-96 VGPR (no spill);
// runtime occupancy 4 blocks/CU when VGPR<=128. sdS/hS swizzled (conflict-free).
__global__ __launch_bounds__(256, 3) void gemm_fused(
    const unsigned short* __restrict__ xp, const unsigned short* __restrict__ Bd,
    const unsigned short* __restrict__ B1, const unsigned short* __restrict__ B2,
    const float* __restrict__ lng, const float* __restrict__ lnb,
    const float* __restrict__ xin, float* __restrict__ outp) {
  __shared__ char smem[40960];
  unsigned short* sdS = (unsigned short*)smem;            // 32 KB: sd frag [4mt][8kc][512] (swizzled)
  unsigned short* hS = (unsigned short*)(smem + 32768);   // 8 KB: h chunk frag (swizzled)
  float* ps1 = (float*)(smem + 36864);                    // 1 KB (aliases hS; disjoint liveness)
  float* ps2 = (float*)(smem + 37888);                    // 1 KB
  unsigned short* swz = (unsigned short*)smem;            // epilogue alias [256][68] = 34816 B

  const int tid = threadIdx.x;
  const int w = tid >> 6;
  const int lane = tid & 63;
  const int g = lane >> 4, c = lane & 15;
  const int MT0 = blockIdx.x << 2;
  const int lsw8 = swz16(lane) * 8; // swizzled fragment-read offset (shorts)

  float pg[4], pb[4];
#pragma unroll
  for (int nt = 0; nt < 4; ++nt) {
    int col = (w << 6) + nt * 16 + c;
    pg[nt] = lng[col]; pb[nt] = lnb[col];
  }

  // ================= G0: freq = xp x Bd (K=256), then LN -> sdS =================
  {
    f32x4 a0[4][4];
#pragma unroll
    for (int i = 0; i < 4; ++i)
#pragma unroll
      for (int j = 0; j < 4; ++j) a0[i][j] = (f32x4){0.f, 0.f, 0.f, 0.f};

    for (int kc = 0; kc < 8; ++kc) {
      bf16x8 af[4];
#pragma unroll
      for (int mt = 0; mt < 4; ++mt)
        af[mt] = *(const bf16x8*)(xp + (((size_t)(MT0 + mt) << 3) + kc) * 512 + lane * 8);
#pragma unroll
      for (int nt = 0; nt < 4; ++nt) {
        bf16x8 bfv = *(const bf16x8*)(Bd + (((size_t)kc << 4) + (w << 2) + nt) * 512 + lane * 8);
#pragma unroll
        for (int mt = 0; mt < 4; ++mt)
          a0[mt][nt] = __builtin_amdgcn_mfma_f32_16x16x32_bf16(af[mt], bfv, a0[mt][nt], 0, 0, 0);
      }
    }

    // LN over 256 cols -> write sdS in swizzled frag layout
#pragma unroll
    for (int mt = 0; mt < 4; ++mt)
#pragma unroll
      for (int r = 0; r < 4; ++r) {
        float s1 = 0.f, s2 = 0.f;
#pragma unroll
        for (int nt = 0; nt < 4; ++nt) { float v = a0[mt][nt][r]; s1 += v; s2 += v * v; }
#pragma unroll
        for (int m = 1; m < 16; m <<= 1) { s1 += __shfl_xor(s1, m, 64); s2 += __shfl_xor(s2, m, 64); }
        if (c == 0) {
          ps1[(w << 6) + mt * 16 + g * 4 + r] = s1;
          ps2[(w << 6) + mt * 16 + g * 4 + r] = s2;
        }
      }
    __syncthreads();
#pragma unroll
    for (int mt = 0; mt < 4; ++mt)
#pragma unroll
      for (int r = 0; r < 4; ++r) {
        int row15 = g * 4 + r;
        int rr = mt * 16 + row15;
        float s1 = ps1[rr] + ps1[64 + rr] + ps1[128 + rr] + ps1[192 + rr];
        float s2 = ps2[rr] + ps2[64 + rr] + ps2[128 + rr] + ps2[192 + rr];
        float mu = s1 * (1.f / 256.f);
        float var = s2 * (1.f / 256.f) - mu * mu;
        float inv = __builtin_amdgcn_rsqf(var + 1e-6f);
#pragma unroll
        for (int nt = 0; nt < 4; ++nt) {
          int col = (w << 6) + nt * 16 + c;
          float v = (a0[mt][nt][r] - mu) * inv * pg[nt] + pb[nt];
          int blk = (((col >> 3) & 3) << 4) | row15;
          sdS[((mt << 3) + (col >> 5)) * 512 + swz16(blk) * 8 + (col & 7)] = f2bf(v);
        }
      }
    __syncthreads();
  }

  // ================= G1 (fc1+ReLU) chained into G2 (fc2 accumulation) =================
  f32x4 acc[4][4]; // fw accumulator (pre-sigmoid)
#pragma unroll
  for (int i = 0; i < 4; ++i)
#pragma unroll
    for (int j = 0; j < 4; ++j) acc[i][j] = (f32x4){0.f, 0.f, 0.f, 0.f};

  for (int hc = 0; hc < 8; ++hc) {
    // ---- G1 partial: h cols [hc*64, +64); wave w owns local cols w*16..+15
    f32x4 a1[4];
#pragma unroll
    for (int mt = 0; mt < 4; ++mt) a1[mt] = (f32x4){0.f, 0.f, 0.f, 0.f};
    const unsigned short* b1p = B1 + (size_t)((hc << 2) + w) * 512 + lane * 8;
    for (int kc = 0; kc < 8; ++kc) {
      bf16x8 bfv = *(const bf16x8*)(b1p + (size_t)kc * 16384);
#pragma unroll
      for (int mt = 0; mt < 4; ++mt) {
        bf16x8 af = *(const bf16x8*)&sdS[((mt << 3) + kc) * 512 + lsw8];
        a1[mt] = __builtin_amdgcn_mfma_f32_16x16x32_bf16(af, bfv, a1[mt], 0, 0, 0);
      }
    }
    // relu -> hS swizzled frag layout; klocal = w*16 + c
#pragma unroll
    for (int mt = 0; mt < 4; ++mt)
#pragma unroll
      for (int r = 0; r < 4; ++r) {
        int row15 = g * 4 + r;
        float v = fmaxf(a1[mt][r], 0.f);
        int blk = (((((w & 1) << 1) | (c >> 3))) << 4) | row15;
        hS[((mt << 1) + (w >> 1)) * 512 + swz16(blk) * 8 + (c & 7)] = f2bf(v);
      }
    __syncthreads();
    // ---- G2 partial: fw += h_chunk x fc2_chunk
#pragma unroll
    for (int kcl = 0; kcl < 2; ++kcl) {
      bf16x8 af2[4];
#pragma unroll
      for (int mt = 0; mt < 4; ++mt)
        af2[mt] = *(const bf16x8*)&hS[((mt << 1) + kcl) * 512 + lsw8];
#pragma unroll
      for (int nt = 0; nt < 4; ++nt) {
        bf16x8 bfv = *(const bf16x8*)(B2 + (size_t)((((hc << 1) + kcl) << 4) + (w << 2) + nt) * 512 +
                                      lane * 8);
#pragma unroll
        for (int mt = 0; mt < 4; ++mt)
          acc[mt][nt] = __builtin_amdgcn_mfma_f32_16x16x32_bf16(af2[mt], bfv, acc[mt][nt], 0, 0, 0);
      }
    }
    __syncthreads(); // before next chunk overwrites hS
  }

  // ================= sigmoid + LN + transposed scale/residual epilogue =================
#pragma unroll
  for (int mt = 0; mt < 4; ++mt)
#pragma unroll
    for (int nt = 0; nt < 4; ++nt)
#pragma unroll
      for (int r = 0; r < 4; ++r)
        acc[mt][nt][r] = __builtin_amdgcn_rcpf(1.f + __expf(-acc[mt][nt][r]));
#pragma unroll
  for (int mt = 0; mt < 4; ++mt)
#pragma unroll
    for (int r = 0; r < 4; ++r) {
      float s1 = 0.f, s2 = 0.f;
#pragma unroll
      for (int nt = 0; nt < 4; ++nt) { float v = acc[mt][nt][r]; s1 += v; s2 += v * v; }
#pragma unroll
      for (int m = 1; m < 16; m <<= 1) { s1 += __shfl_xor(s1, m, 64); s2 += __shfl_xor(s2, m, 64); }
      if (c == 0) {
        ps1[(w << 6) + mt * 16 + g * 4 + r] = s1;
        ps2[(w << 6) + mt * 16 + g * 4 + r] = s2;
      }
    }
  __syncthreads();
  float mu_[4][4], inv_[4][4];
#pragma unroll
  for (int mt = 0; mt < 4; ++mt)
#pragma unroll
    for (int r = 0; r < 4; ++r) {
      int rr = mt * 16 + g * 4 + r;
      float s1 = ps1[rr] + ps1[64 + rr] + ps1[128 + rr] + ps1[192 + rr];
      float s2 = ps2[rr] + ps2[64 + rr] + ps2[128 + rr] + ps2[192 + rr];
      float mu = s1 * (1.f / 256.f);
      float var = s2 * (1.f / 256.f) - mu * mu;
      mu_[mt][r] = mu;
      inv_[mt][r] = __builtin_amdgcn_rsqf(var + 1e-6f);
    }
#pragma unroll
  for (int mt = 0; mt < 4; ++mt)
#pragma unroll
    for (int nt = 0; nt < 4; ++nt) {
      alignas(8) unsigned short tmp[4];
#pragma unroll
      for (int r = 0; r < 4; ++r)
        tmp[r] = f2bf((acc[mt][nt][r] - mu_[mt][r]) * inv_[mt][r] * pg[nt] + pb[nt]);
      int col = (w << 6) + nt * 16 + c;
      *(uint2*)&swz[col * 68 + mt * 16 + g * 4] = *(const uint2*)tmp;
    }
  __syncthreads();
  {
    const int row0 = MT0 << 4;
    const int b = row0 >> 12;
    const int l0 = row0 & 4095;
    const int li = tid & 63, cq = tid >> 6;
    const size_t xbase = (size_t)(MT0 + (li >> 4)) * 4096 + (size_t)(li & 15) * 8;
    const size_t obase = ((size_t)((b << 8) + (cq << 6))) * LL + l0 + li;
#pragma unroll
    for (int i8 = 0; i8 < 8; ++i8) {
      bf16x8 xq = *(const bf16x8*)&xp[xbase + (size_t)((cq << 1) + (i8 >> 2)) * 512 +
                                      (size_t)(i8 & 3) * 128];
#pragma unroll
      for (int j = 0; j < 8; ++j) {
        int ic = (i8 << 3) + j;
        int ccol = (cq << 6) + ic;
        float fwv = bf2f(swz[ccol * 68 + li]);
        float xpv = bf2f((unsigned short)xq[j]);
        size_t o = obase + (size_t)ic * LL;
        float ov = fmaf(xpv, fwv, xin[o]);
        outp[o] = fmaxf(ov, 0.f);
      }
    }
  }
}

extern "C" void kernel_launch(void* const* d_in, const int* in_sizes, int n_in,
                              void* d_out, int out_size, void* d_ws, size_t ws_size,
                              hipStream_t stream) {
  const float* x    = (const float*)d_in[0];
  const float* w1   = (const float*)d_in[1];
  const float* g1   = (const float*)d_in[2];
  const float* b1   = (const float*)d_in[3];
  const float* m1   = (const float*)d_in[4];
  const float* v1   = (const float*)d_in[5];
  const float* w2   = (const float*)d_in[6];
  const float* g2   = (const float*)d_in[7];
  const float* b2   = (const float*)d_in[8];
  const float* m2   = (const float*)d_in[9];
  const float* v2   = (const float*)d_in[10];
  const float* fc1  = (const float*)d_in[11];
  const float* fc2  = (const float*)d_in[12];
  const float* lng  = (const float*)d_in[13];
  const float* lnb  = (const float*)d_in[14];
  float* out = (float*)d_out;

  float* ws = (float*)d_ws;
  float* b1f = ws;                                        // 256
  float* b2f = ws + 256;                                  // 256
  unsigned short* Bd   = (unsigned short*)(ws + 512);     // 65536 bf16
  unsigned short* B1   = (unsigned short*)(ws + 33280);   // 131072 bf16
  unsigned short* B2   = (unsigned short*)(ws + 98816);   // 131072 bf16
  unsigned short* W1sw = (unsigned short*)(ws + 164352);  // 196608 bf16
  unsigned short* W2sw = (unsigned short*)(ws + 262656);  // 196608 bf16
  unsigned short* xT    = (unsigned short*)(ws + 360960);    // 33554432 bf16
  unsigned short* y1T  = (unsigned short*)(ws + 17138176);   // 33554432 bf16
  unsigned short* xp_sw = (unsigned short*)(ws + 50692608);  // 33554432 bf16
  // total 67469824 floats = 269.9 MB

  init_bias<<<1, 256, 0, stream>>>(g1, b1, m1, v1, g2, b2, m2, v2, b1f, b2f);
  init_wsw<<<1536, 256, 0, stream>>>(w1, g1, v1, w2, g2, v2, W1sw, W2sw);
  init_bsw<<<1280, 256, 0, stream>>>(fc1, fc2, Bd, B1, B2);

  transpose_x<<<dim3(64, 4, 32), 256, 0, stream>>>(x, xT);

  conv_mfma<true, false><<<dim3(64, 32), 256, 0, stream>>>(xT, W1sw, b1f, y1T);
  conv_mfma<false, true><<<dim3(64, 32), 256, 0, stream>>>(y1T, W2sw, b2f, xp_sw);

  gemm_fused<<<2048, 256, 0, stream>>>(xp_sw, Bd, B1, B2, lng, lnb, x, out);
}

// Round 5
// 621.773 us; speedup vs baseline: 1.1459x; 1.1459x over previous
//
#include <hip/hip_runtime.h>
#include <math.h>

#define BB 32
#define CC 256
#define LL 4096

typedef __attribute__((ext_vector_type(8))) short bf16x8;
typedef __attribute__((ext_vector_type(4))) float f32x4;

__device__ __forceinline__ unsigned short f2bf(float f) {
  unsigned u = __float_as_uint(f);
  u = (u + 0x7FFFu + ((u >> 16) & 1u)) >> 16;
  return (unsigned short)u;
}
__device__ __forceinline__ float bf2f(unsigned short v) {
  return __uint_as_float(((unsigned)v) << 16);
}
// XOR-swizzle of a 16B-block index within a 1KB chunk (applied on both store & load)
__device__ __forceinline__ int swz16(int blk) { return blk ^ ((blk >> 3) & 7); }

// async global->LDS, 16B per lane; LDS dest = uniform base + lane*16
__device__ __forceinline__ void gload_lds16(const unsigned short* g, unsigned short* l) {
  __builtin_amdgcn_global_load_lds(
      (const __attribute__((address_space(1))) unsigned int*)g,
      (__attribute__((address_space(3))) unsigned int*)l, 16, 0, 0);
}

// ---------------- init: biases (BN folded) ----------------
__global__ void init_bias(const float* __restrict__ g1, const float* __restrict__ b1,
                          const float* __restrict__ m1, const float* __restrict__ v1,
                          const float* __restrict__ g2, const float* __restrict__ b2,
                          const float* __restrict__ m2, const float* __restrict__ v2,
                          float* __restrict__ b1f, float* __restrict__ b2f) {
  int c = threadIdx.x;
  b1f[c] = b1[c] - m1[c] * g1[c] * rsqrtf(v1[c] + 1e-5f);
  b2f[c] = b2[c] - m2[c] * g2[c] * rsqrtf(v2[c] + 1e-5f);
}

// ---------------- init: conv weights, B-frag-linear bf16, BN-folded ----------------
__global__ void init_wsw(const float* __restrict__ w1, const float* __restrict__ g1,
                         const float* __restrict__ v1,
                         const float* __restrict__ w2, const float* __restrict__ g2,
                         const float* __restrict__ v2,
                         unsigned short* __restrict__ W1sw, unsigned short* __restrict__ W2sw) {
  int id = blockIdx.x * 256 + threadIdx.x; // 393216
  int cv = id / 196608;
  int i = id - cv * 196608;
  int kc3t = i >> 13;
  int kc = kc3t / 3, t = kc3t - 3 * kc;
  int rem = i & 8191;
  int nt = rem >> 9, L = (rem >> 3) & 63, j = i & 7;
  int co = nt * 16 + (L & 15);
  int ci = kc * 32 + ((L >> 4) << 3) + j;
  if (cv == 0) {
    float s = g1[co] * rsqrtf(v1[co] + 1e-5f);
    W1sw[i] = f2bf(w1[(co * 256 + ci) * 3 + t] * s);
  } else {
    float s = g2[co] * rsqrtf(v2[co] + 1e-5f);
    W2sw[i] = f2bf(w2[(co * 256 + ci) * 3 + t] * s);
  }
}

// ---------------- init: GEMM-chain B matrices, frag-linear bf16 ----------------
__global__ void init_bsw(const float* __restrict__ fc1, const float* __restrict__ fc2,
                         unsigned short* __restrict__ Bd, unsigned short* __restrict__ B1,
                         unsigned short* __restrict__ B2) {
  int id = blockIdx.x * 256 + threadIdx.x; // 327680 total
  if (id < 65536) {
    int i = id;
    int kc = i >> 13, nt = (i >> 9) & 15, L = (i >> 3) & 63, j = i & 7;
    int n = nt * 16 + (L & 15), k = kc * 32 + (L >> 4) * 8 + j;
    // exact integer phase reduction mod 1024, then single-precision cos
    int m = (n * (2 * k + 1)) & 1023;
    float v = 2.0f * cosf(3.14159265358979323846f * (float)m * (1.0f / 512.0f));
    Bd[i] = f2bf(v);
  } else if (id < 65536 + 131072) {
    int i = id - 65536;
    int kc = i >> 14, nt = (i >> 9) & 31, L = (i >> 3) & 63, j = i & 7;
    int n = nt * 16 + (L & 15), k = kc * 32 + (L >> 4) * 8 + j;
    B1[i] = f2bf(fc1[n * 256 + k]);
  } else {
    int i = id - 65536 - 131072;
    int kc = i >> 13, nt = (i >> 9) & 15, L = (i >> 3) & 63, j = i & 7;
    int n = nt * 16 + (L & 15), k = kc * 32 + (L >> 4) * 8 + j;
    B2[i] = f2bf(fc2[n * 512 + k]);
  }
}

// ---------------- transpose: x fp32 [b][ci][l] -> xT bf16 [b][l][ci] ----------------
__global__ __launch_bounds__(256) void transpose_x(const float* __restrict__ x,
                                                   unsigned short* __restrict__ xT) {
  __shared__ unsigned short ts[64][68];
  const int tid = threadIdx.x;
  const int b = blockIdx.z, ci0 = blockIdx.y << 6, l0 = blockIdx.x << 6;
#pragma unroll
  for (int p = 0; p < 4; ++p) {
    int cc = (p << 4) + (tid >> 4);
    int ll = (tid & 15) << 2;
    float4 v = *(const float4*)&x[((((size_t)b << 8) + ci0 + cc) << 12) + l0 + ll];
    ts[ll + 0][cc] = f2bf(v.x);
    ts[ll + 1][cc] = f2bf(v.y);
    ts[ll + 2][cc] = f2bf(v.z);
    ts[ll + 3][cc] = f2bf(v.w);
  }
  __syncthreads();
#pragma unroll
  for (int p = 0; p < 4; ++p) {
    int idx = tid + (p << 8);
    int row = idx >> 4, ch = idx & 15;
    uint2 v = *(const uint2*)&ts[row][ch << 2];
    *(uint2*)&xT[((((size_t)b << 12) + l0 + row) << 8) + ci0 + (ch << 2)] = v;
  }
}

// ---------------- conv as implicit GEMM (MFMA bf16 16x16x32) ----------------
// block: 64 l x 256 co, one b. K = (8 ci-chunks) x (3 taps).
// W staged per-chunk into LDS via global_load_lds (r3 measured-best form).
template <bool RELU, bool FRAGOUT>
__global__ __launch_bounds__(256, 3) void conv_mfma(
    const unsigned short* __restrict__ inT, const unsigned short* __restrict__ Wsw,
    const float* __restrict__ bias, unsigned short* __restrict__ outT) {
  __shared__ char smem[51232];
  unsigned short* xs = (unsigned short*)smem;              // [66][264]
  unsigned short* smemB = (unsigned short*)(smem + 34848); // 16 KB chunk (8192 shorts)
  unsigned short* swz = (unsigned short*)smem;             // epilogue alias [64][264]

  const int tid = threadIdx.x;
  const int w = tid >> 6, lane = tid & 63;
  const int g = lane >> 4, c = lane & 15;
  const int l0 = blockIdx.x << 6;
  const int b = blockIdx.y;
  const size_t rowbase = ((size_t)b << 12) + l0;

  // stage xs: rows l0-1 .. l0+64 (66), 256 ci each
  for (int idx = tid; idx < 66 * 32; idx += 256) {
    int r = idx >> 5, ch = idx & 31;
    int gl = l0 - 1 + r;
    uint4 v = {0, 0, 0, 0};
    if (gl >= 0 && gl < LL)
      v = *(const uint4*)&inT[((((size_t)b << 12) + gl) << 8) + (ch << 3)];
    *(uint4*)&xs[r * 264 + (ch << 3)] = v;
  }

  f32x4 acc[4][4];
#pragma unroll
  for (int i = 0; i < 4; ++i)
#pragma unroll
    for (int j = 0; j < 4; ++j) acc[i][j] = (f32x4){0.f, 0.f, 0.f, 0.f};

  for (int kc = 0; kc < 8; ++kc)
#pragma unroll
    for (int t = 0; t < 3; ++t) {
      __syncthreads();
      const unsigned short* src = Wsw + ((kc * 3 + t) << 13);
      {
        const unsigned short* gs = src + (w << 11) + (lane << 3);
        unsigned short* ls = smemB + (w << 11);
        gload_lds16(gs, ls);
        gload_lds16(gs + 512, ls + 512);
        gload_lds16(gs + 1024, ls + 1024);
        gload_lds16(gs + 1536, ls + 1536);
      }
      __syncthreads();
      bf16x8 af[4];
#pragma unroll
      for (int mt = 0; mt < 4; ++mt)
        af[mt] = *(const bf16x8*)&xs[(mt * 16 + c + t) * 264 + (kc << 5) + (g << 3)];
#pragma unroll
      for (int nt = 0; nt < 4; ++nt) {
        bf16x8 bfv = *(const bf16x8*)&smemB[((w << 2) + nt) * 512 + (lane << 3)];
#pragma unroll
        for (int mt = 0; mt < 4; ++mt)
          acc[mt][nt] = __builtin_amdgcn_mfma_f32_16x16x32_bf16(af[mt], bfv, acc[mt][nt], 0, 0, 0);
      }
    }
  __syncthreads();

  float pb[4];
#pragma unroll
  for (int nt = 0; nt < 4; ++nt) pb[nt] = bias[(w << 6) + nt * 16 + c];
#pragma unroll
  for (int mt = 0; mt < 4; ++mt)
#pragma unroll
    for (int r = 0; r < 4; ++r) {
      int row = mt * 16 + g * 4 + r;
#pragma unroll
      for (int nt = 0; nt < 4; ++nt) {
        float v = acc[mt][nt][r] + pb[nt];
        if (RELU) v = fmaxf(v, 0.f);
        swz[row * 264 + (w << 6) + nt * 16 + c] = f2bf(v);
      }
    }
  __syncthreads();
  if (!FRAGOUT) {
#pragma unroll
    for (int i = 0; i < 8; ++i) {
      int idx = tid + (i << 8);
      int row = idx >> 5, ch = idx & 31;
      *(uint4*)&outT[((rowbase + row) << 8) + (ch << 3)] = *(const uint4*)&swz[row * 264 + (ch << 3)];
    }
  } else {
    const int MT0 = (int)(rowbase >> 4);
#pragma unroll
    for (int i = 0; i < 8; ++i) {
      int f = tid + (i << 8);
      int mtl = f >> 9, kcl = (f >> 6) & 7, L = f & 63;
      int row = mtl * 16 + (L & 15), k0 = (kcl << 5) + ((L >> 4) << 3);
      uint4 v = *(const uint4*)&swz[row * 264 + k0];
      *(uint4*)&outT[(((size_t)(MT0 + mtl) * 8 + kcl) << 9) + L * 8] = v;
    }
  }
}

// ---------------- FULLY FUSED GEMM chain ----------------
// r3-measured-best occupancy config: launch_bounds (256,4), LDS 40960 B.
// sdS/hS swizzled (conflict-free). Vectorized float4 epilogue (16 ld + 16 st per thread).
__global__ __launch_bounds__(256, 4) void gemm_fused(
    const unsigned short* __restrict__ xp, const unsigned short* __restrict__ Bd,
    const unsigned short* __restrict__ B1, const unsigned short* __restrict__ B2,
    const float* __restrict__ lng, const float* __restrict__ lnb,
    const float* __restrict__ xin, float* __restrict__ outp) {
  __shared__ char smem[40960];
  unsigned short* sdS = (unsigned short*)smem;            // 32 KB: sd frag [4mt][8kc][512] (swizzled)
  unsigned short* hS = (unsigned short*)(smem + 32768);   // 8 KB: h chunk frag (swizzled)
  float* ps1 = (float*)(smem + 36864);                    // 1 KB (aliases hS; disjoint liveness)
  float* ps2 = (float*)(smem + 37888);                    // 1 KB
  unsigned short* swz = (unsigned short*)smem;            // epilogue alias [256][68] = 34816 B

  const int tid = threadIdx.x;
  const int w = tid >> 6;
  const int lane = tid & 63;
  const int g = lane >> 4, c = lane & 15;
  const int MT0 = blockIdx.x << 2;
  const int lsw8 = swz16(lane) * 8; // swizzled fragment-read offset (shorts)

  float pg[4], pb[4];
#pragma unroll
  for (int nt = 0; nt < 4; ++nt) {
    int col = (w << 6) + nt * 16 + c;
    pg[nt] = lng[col]; pb[nt] = lnb[col];
  }

  // ================= G0: freq = xp x Bd (K=256), then LN -> sdS =================
  {
    f32x4 a0[4][4];
#pragma unroll
    for (int i = 0; i < 4; ++i)
#pragma unroll
      for (int j = 0; j < 4; ++j) a0[i][j] = (f32x4){0.f, 0.f, 0.f, 0.f};

    for (int kc = 0; kc < 8; ++kc) {
      bf16x8 af[4];
#pragma unroll
      for (int mt = 0; mt < 4; ++mt)
        af[mt] = *(const bf16x8*)(xp + (((size_t)(MT0 + mt) << 3) + kc) * 512 + lane * 8);
#pragma unroll
      for (int nt = 0; nt < 4; ++nt) {
        bf16x8 bfv = *(const bf16x8*)(Bd + (((size_t)kc << 4) + (w << 2) + nt) * 512 + lane * 8);
#pragma unroll
        for (int mt = 0; mt < 4; ++mt)
          a0[mt][nt] = __builtin_amdgcn_mfma_f32_16x16x32_bf16(af[mt], bfv, a0[mt][nt], 0, 0, 0);
      }
    }

    // LN over 256 cols -> write sdS in swizzled frag layout
#pragma unroll
    for (int mt = 0; mt < 4; ++mt)
#pragma unroll
      for (int r = 0; r < 4; ++r) {
        float s1 = 0.f, s2 = 0.f;
#pragma unroll
        for (int nt = 0; nt < 4; ++nt) { float v = a0[mt][nt][r]; s1 += v; s2 += v * v; }
#pragma unroll
        for (int m = 1; m < 16; m <<= 1) { s1 += __shfl_xor(s1, m, 64); s2 += __shfl_xor(s2, m, 64); }
        if (c == 0) {
          ps1[(w << 6) + mt * 16 + g * 4 + r] = s1;
          ps2[(w << 6) + mt * 16 + g * 4 + r] = s2;
        }
      }
    __syncthreads();
#pragma unroll
    for (int mt = 0; mt < 4; ++mt)
#pragma unroll
      for (int r = 0; r < 4; ++r) {
        int row15 = g * 4 + r;
        int rr = mt * 16 + row15;
        float s1 = ps1[rr] + ps1[64 + rr] + ps1[128 + rr] + ps1[192 + rr];
        float s2 = ps2[rr] + ps2[64 + rr] + ps2[128 + rr] + ps2[192 + rr];
        float mu = s1 * (1.f / 256.f);
        float var = s2 * (1.f / 256.f) - mu * mu;
        float inv = __builtin_amdgcn_rsqf(var + 1e-6f);
#pragma unroll
        for (int nt = 0; nt < 4; ++nt) {
          int col = (w << 6) + nt * 16 + c;
          float v = (a0[mt][nt][r] - mu) * inv * pg[nt] + pb[nt];
          int blk = (((col >> 3) & 3) << 4) | row15;
          sdS[((mt << 3) + (col >> 5)) * 512 + swz16(blk) * 8 + (col & 7)] = f2bf(v);
        }
      }
    __syncthreads();
  }

  // ================= G1 (fc1+ReLU) chained into G2 (fc2 accumulation) =================
  f32x4 acc[4][4]; // fw accumulator (pre-sigmoid)
#pragma unroll
  for (int i = 0; i < 4; ++i)
#pragma unroll
    for (int j = 0; j < 4; ++j) acc[i][j] = (f32x4){0.f, 0.f, 0.f, 0.f};

  for (int hc = 0; hc < 8; ++hc) {
    // ---- G1 partial: h cols [hc*64, +64); wave w owns local cols w*16..+15
    f32x4 a1[4];
#pragma unroll
    for (int mt = 0; mt < 4; ++mt) a1[mt] = (f32x4){0.f, 0.f, 0.f, 0.f};
    const unsigned short* b1p = B1 + (size_t)((hc << 2) + w) * 512 + lane * 8;
    for (int kc = 0; kc < 8; ++kc) {
      bf16x8 bfv = *(const bf16x8*)(b1p + (size_t)kc * 16384);
#pragma unroll
      for (int mt = 0; mt < 4; ++mt) {
        bf16x8 af = *(const bf16x8*)&sdS[((mt << 3) + kc) * 512 + lsw8];
        a1[mt] = __builtin_amdgcn_mfma_f32_16x16x32_bf16(af, bfv, a1[mt], 0, 0, 0);
      }
    }
    // relu -> hS swizzled frag layout; klocal = w*16 + c
#pragma unroll
    for (int mt = 0; mt < 4; ++mt)
#pragma unroll
      for (int r = 0; r < 4; ++r) {
        int row15 = g * 4 + r;
        float v = fmaxf(a1[mt][r], 0.f);
        int blk = (((((w & 1) << 1) | (c >> 3))) << 4) | row15;
        hS[((mt << 1) + (w >> 1)) * 512 + swz16(blk) * 8 + (c & 7)] = f2bf(v);
      }
    __syncthreads();
    // ---- G2 partial: fw += h_chunk x fc2_chunk
#pragma unroll
    for (int kcl = 0; kcl < 2; ++kcl) {
      bf16x8 af2[4];
#pragma unroll
      for (int mt = 0; mt < 4; ++mt)
        af2[mt] = *(const bf16x8*)&hS[((mt << 1) + kcl) * 512 + lsw8];
#pragma unroll
      for (int nt = 0; nt < 4; ++nt) {
        bf16x8 bfv = *(const bf16x8*)(B2 + (size_t)((((hc << 1) + kcl) << 4) + (w << 2) + nt) * 512 +
                                      lane * 8);
#pragma unroll
        for (int mt = 0; mt < 4; ++mt)
          acc[mt][nt] = __builtin_amdgcn_mfma_f32_16x16x32_bf16(af2[mt], bfv, acc[mt][nt], 0, 0, 0);
      }
    }
    __syncthreads(); // before next chunk overwrites hS
  }

  // ================= sigmoid + LN -> swz (bf16 [256 col][68]) =================
#pragma unroll
  for (int mt = 0; mt < 4; ++mt)
#pragma unroll
    for (int nt = 0; nt < 4; ++nt)
#pragma unroll
      for (int r = 0; r < 4; ++r)
        acc[mt][nt][r] = __builtin_amdgcn_rcpf(1.f + __expf(-acc[mt][nt][r]));
#pragma unroll
  for (int mt = 0; mt < 4; ++mt)
#pragma unroll
    for (int r = 0; r < 4; ++r) {
      float s1 = 0.f, s2 = 0.f;
#pragma unroll
      for (int nt = 0; nt < 4; ++nt) { float v = acc[mt][nt][r]; s1 += v; s2 += v * v; }
#pragma unroll
      for (int m = 1; m < 16; m <<= 1) { s1 += __shfl_xor(s1, m, 64); s2 += __shfl_xor(s2, m, 64); }
      if (c == 0) {
        ps1[(w << 6) + mt * 16 + g * 4 + r] = s1;
        ps2[(w << 6) + mt * 16 + g * 4 + r] = s2;
      }
    }
  __syncthreads();
#pragma unroll
  for (int mt = 0; mt < 4; ++mt) {
    float muv[4], invv[4];
#pragma unroll
    for (int r = 0; r < 4; ++r) {
      int rr = mt * 16 + g * 4 + r;
      float s1 = ps1[rr] + ps1[64 + rr] + ps1[128 + rr] + ps1[192 + rr];
      float s2 = ps2[rr] + ps2[64 + rr] + ps2[128 + rr] + ps2[192 + rr];
      float mu = s1 * (1.f / 256.f);
      float var = s2 * (1.f / 256.f) - mu * mu;
      muv[r] = mu;
      invv[r] = __builtin_amdgcn_rsqf(var + 1e-6f);
    }
#pragma unroll
    for (int nt = 0; nt < 4; ++nt) {
      alignas(8) unsigned short tmp[4];
#pragma unroll
      for (int r = 0; r < 4; ++r)
        tmp[r] = f2bf((acc[mt][nt][r] - muv[r]) * invv[r] * pg[nt] + pb[nt]);
      int col = (w << 6) + nt * 16 + c;
      *(uint2*)&swz[col * 68 + mt * 16 + g * 4] = *(const uint2*)tmp;
    }
  }
  __syncthreads();

  // ================= vectorized scale/residual epilogue (float4) =================
  // thread: fq = l-quad (l = fq*4..fq*4+3), handles 16 ccols (ccol = cg + 16*i).
  // Wave instr: 16 lanes/ccol cover fq 0-15 -> 256 B contiguous per ccol.
  {
    const int row0 = MT0 << 4;
    const int b = row0 >> 12;
    const int l0 = row0 & 4095;
    const int fq = tid & 15, cg = tid >> 4;
    const int lq = fq << 2;        // l base within block
    const int lhi = fq >> 2;       // l >> 4
    const int llo = (fq & 3) << 2; // (l & 15) base
#pragma unroll
    for (int i = 0; i < 16; ++i) {
      int ccol = cg + (i << 4);
      alignas(8) unsigned short fw4[4];
      *(uint2*)fw4 = *(const uint2*)&swz[ccol * 68 + lq];
      const unsigned short* xpp = xp + (((size_t)(MT0 + lhi) * 8 + (ccol >> 5)) << 9) +
                                  (((((ccol >> 3) & 3) << 4) + llo) << 3) + (ccol & 7);
      size_t o = (((size_t)((b << 8) + ccol)) << 12) + l0 + lq;
      float4 xv = *(const float4*)&xin[o];
      float4 ov;
      ov.x = fmaxf(fmaf(bf2f(xpp[0]),  bf2f(fw4[0]), xv.x), 0.f);
      ov.y = fmaxf(fmaf(bf2f(xpp[8]),  bf2f(fw4[1]), xv.y), 0.f);
      ov.z = fmaxf(fmaf(bf2f(xpp[16]), bf2f(fw4[2]), xv.z), 0.f);
      ov.w = fmaxf(fmaf(bf2f(xpp[24]), bf2f(fw4[3]), xv.w), 0.f);
      *(float4*)&outp[o] = ov;
    }
  }
}

extern "C" void kernel_launch(void* const* d_in, const int* in_sizes, int n_in,
                              void* d_out, int out_size, void* d_ws, size_t ws_size,
                              hipStream_t stream) {
  const float* x    = (const float*)d_in[0];
  const float* w1   = (const float*)d_in[1];
  const float* g1   = (const float*)d_in[2];
  const float* b1   = (const float*)d_in[3];
  const float* m1   = (const float*)d_in[4];
  const float* v1   = (const float*)d_in[5];
  const float* w2   = (const float*)d_in[6];
  const float* g2   = (const float*)d_in[7];
  const float* b2   = (const float*)d_in[8];
  const float* m2   = (const float*)d_in[9];
  const float* v2   = (const float*)d_in[10];
  const float* fc1  = (const float*)d_in[11];
  const float* fc2  = (const float*)d_in[12];
  const float* lng  = (const float*)d_in[13];
  const float* lnb  = (const float*)d_in[14];
  float* out = (float*)d_out;

  float* ws = (float*)d_ws;
  float* b1f = ws;                                        // 256
  float* b2f = ws + 256;                                  // 256
  unsigned short* Bd   = (unsigned short*)(ws + 512);     // 65536 bf16
  unsigned short* B1   = (unsigned short*)(ws + 33280);   // 131072 bf16
  unsigned short* B2   = (unsigned short*)(ws + 98816);   // 131072 bf16
  unsigned short* W1sw = (unsigned short*)(ws + 164352);  // 196608 bf16
  unsigned short* W2sw = (unsigned short*)(ws + 262656);  // 196608 bf16
  unsigned short* xT    = (unsigned short*)(ws + 360960);    // 33554432 bf16
  unsigned short* y1T  = (unsigned short*)(ws + 17138176);   // 33554432 bf16
  unsigned short* xp_sw = (unsigned short*)(ws + 50692608);  // 33554432 bf16
  // total 67469824 floats = 269.9 MB

  init_bias<<<1, 256, 0, stream>>>(g1, b1, m1, v1, g2, b2, m2, v2, b1f, b2f);
  init_wsw<<<1536, 256, 0, stream>>>(w1, g1, v1, w2, g2, v2, W1sw, W2sw);
  init_bsw<<<1280, 256, 0, stream>>>(fc1, fc2, Bd, B1, B2);

  transpose_x<<<dim3(64, 4, 32), 256, 0, stream>>>(x, xT);

  conv_mfma<true, false><<<dim3(64, 32), 256, 0, stream>>>(xT, W1sw, b1f, y1T);
  conv_mfma<false, true><<<dim3(64, 32), 256, 0, stream>>>(y1T, W2sw, b2f, xp_sw);

  gemm_fused<<<2048, 256, 0, stream>>>(xp_sw, Bd, B1, B2, lng, lnb, x, out);
}

// Round 6
// 586.293 us; speedup vs baseline: 1.2152x; 1.0605x over previous
//
#include <hip/hip_runtime.h>
#include <math.h>

#define BB 32
#define CC 256
#define LL 4096

typedef __attribute__((ext_vector_type(8))) short bf16x8;
typedef __attribute__((ext_vector_type(4))) float f32x4;

__device__ __forceinline__ unsigned short f2bf(float f) {
  unsigned u = __float_as_uint(f);
  u = (u + 0x7FFFu + ((u >> 16) & 1u)) >> 16;
  return (unsigned short)u;
}
__device__ __forceinline__ float bf2f(unsigned short v) {
  return __uint_as_float(((unsigned)v) << 16);
}
// XOR-swizzle of a 16B-block index within a 1KB chunk (applied on both store & load)
__device__ __forceinline__ int swz16(int blk) { return blk ^ ((blk >> 3) & 7); }

// async global->LDS, 16B per lane; LDS dest = wave-uniform base + lane*16
__device__ __forceinline__ void gload_lds16(const unsigned short* g, unsigned short* l) {
  __builtin_amdgcn_global_load_lds(
      (const __attribute__((address_space(1))) unsigned int*)g,
      (__attribute__((address_space(3))) unsigned int*)l, 16, 0, 0);
}

// ---------------- init: biases (BN folded) ----------------
__global__ void init_bias(const float* __restrict__ g1, const float* __restrict__ b1,
                          const float* __restrict__ m1, const float* __restrict__ v1,
                          const float* __restrict__ g2, const float* __restrict__ b2,
                          const float* __restrict__ m2, const float* __restrict__ v2,
                          float* __restrict__ b1f, float* __restrict__ b2f) {
  int c = threadIdx.x;
  b1f[c] = b1[c] - m1[c] * g1[c] * rsqrtf(v1[c] + 1e-5f);
  b2f[c] = b2[c] - m2[c] * g2[c] * rsqrtf(v2[c] + 1e-5f);
}

// ---------------- init: conv weights, B-frag-linear bf16, BN-folded ----------------
__global__ void init_wsw(const float* __restrict__ w1, const float* __restrict__ g1,
                         const float* __restrict__ v1,
                         const float* __restrict__ w2, const float* __restrict__ g2,
                         const float* __restrict__ v2,
                         unsigned short* __restrict__ W1sw, unsigned short* __restrict__ W2sw) {
  int id = blockIdx.x * 256 + threadIdx.x; // 393216
  int cv = id / 196608;
  int i = id - cv * 196608;
  int kc3t = i >> 13;
  int kc = kc3t / 3, t = kc3t - 3 * kc;
  int rem = i & 8191;
  int nt = rem >> 9, L = (rem >> 3) & 63, j = i & 7;
  int co = nt * 16 + (L & 15);
  int ci = kc * 32 + ((L >> 4) << 3) + j;
  if (cv == 0) {
    float s = g1[co] * rsqrtf(v1[co] + 1e-5f);
    W1sw[i] = f2bf(w1[(co * 256 + ci) * 3 + t] * s);
  } else {
    float s = g2[co] * rsqrtf(v2[co] + 1e-5f);
    W2sw[i] = f2bf(w2[(co * 256 + ci) * 3 + t] * s);
  }
}

// ---------------- init: GEMM-chain B matrices, frag-linear bf16 ----------------
__global__ void init_bsw(const float* __restrict__ fc1, const float* __restrict__ fc2,
                         unsigned short* __restrict__ Bd, unsigned short* __restrict__ B1,
                         unsigned short* __restrict__ B2) {
  int id = blockIdx.x * 256 + threadIdx.x; // 327680 total
  if (id < 65536) {
    int i = id;
    int kc = i >> 13, nt = (i >> 9) & 15, L = (i >> 3) & 63, j = i & 7;
    int n = nt * 16 + (L & 15), k = kc * 32 + (L >> 4) * 8 + j;
    // exact integer phase reduction mod 1024, then single-precision cos
    int m = (n * (2 * k + 1)) & 1023;
    float v = 2.0f * cosf(3.14159265358979323846f * (float)m * (1.0f / 512.0f));
    Bd[i] = f2bf(v);
  } else if (id < 65536 + 131072) {
    int i = id - 65536;
    int kc = i >> 14, nt = (i >> 9) & 31, L = (i >> 3) & 63, j = i & 7;
    int n = nt * 16 + (L & 15), k = kc * 32 + (L >> 4) * 8 + j;
    B1[i] = f2bf(fc1[n * 256 + k]);
  } else {
    int i = id - 65536 - 131072;
    int kc = i >> 13, nt = (i >> 9) & 15, L = (i >> 3) & 63, j = i & 7;
    int n = nt * 16 + (L & 15), k = kc * 32 + (L >> 4) * 8 + j;
    B2[i] = f2bf(fc2[n * 512 + k]);
  }
}

// ---------------- transpose: x fp32 [b][ci][l] -> xT bf16 [b][l][ci] ----------------
__global__ __launch_bounds__(256) void transpose_x(const float* __restrict__ x,
                                                   unsigned short* __restrict__ xT) {
  __shared__ unsigned short ts[64][68];
  const int tid = threadIdx.x;
  const int b = blockIdx.z, ci0 = blockIdx.y << 6, l0 = blockIdx.x << 6;
#pragma unroll
  for (int p = 0; p < 4; ++p) {
    int cc = (p << 4) + (tid >> 4);
    int ll = (tid & 15) << 2;
    float4 v = *(const float4*)&x[((((size_t)b << 8) + ci0 + cc) << 12) + l0 + ll];
    ts[ll + 0][cc] = f2bf(v.x);
    ts[ll + 1][cc] = f2bf(v.y);
    ts[ll + 2][cc] = f2bf(v.z);
    ts[ll + 3][cc] = f2bf(v.w);
  }
  __syncthreads();
#pragma unroll
  for (int p = 0; p < 4; ++p) {
    int idx = tid + (p << 8);
    int row = idx >> 4, ch = idx & 15;
    uint2 v = *(const uint2*)&ts[row][ch << 2];
    *(uint2*)&xT[((((size_t)b << 12) + l0 + row) << 8) + ci0 + (ch << 2)] = v;
  }
}

// ---------------- conv as implicit GEMM (MFMA bf16 16x16x32) ----------------
// block: 64 l x 256 co, one b. K = (8 ci-chunks) x (3 taps).
// W staged per-chunk into WAVE-PRIVATE 4KB LDS via global_load_lds -> NO barriers
// in the K-loop; per-wave s_waitcnt only. lgkmcnt(0) before re-stage guards the
// single buffer; vmcnt(0)+sched_barrier fences the ds_read (rule-18).
template <bool RELU, bool FRAGOUT>
__global__ __launch_bounds__(256, 3) void conv_mfma(
    const unsigned short* __restrict__ inT, const unsigned short* __restrict__ Wsw,
    const float* __restrict__ bias, unsigned short* __restrict__ outT) {
  __shared__ char smem[51232];
  unsigned short* xs = (unsigned short*)smem;              // [66][264]
  unsigned short* smemB = (unsigned short*)(smem + 34848); // 16 KB = 4 waves x 4KB private
  unsigned short* swz = (unsigned short*)smem;             // epilogue alias [64][264]

  const int tid = threadIdx.x;
  const int w = tid >> 6, lane = tid & 63;
  const int g = lane >> 4, c = lane & 15;
  const int l0 = blockIdx.x << 6;
  const int b = blockIdx.y;
  const size_t rowbase = ((size_t)b << 12) + l0;

  // stage xs: rows l0-1 .. l0+64 (66), 256 ci each
  for (int idx = tid; idx < 66 * 32; idx += 256) {
    int r = idx >> 5, ch = idx & 31;
    int gl = l0 - 1 + r;
    uint4 v = {0, 0, 0, 0};
    if (gl >= 0 && gl < LL)
      v = *(const uint4*)&inT[((((size_t)b << 12) + gl) << 8) + (ch << 3)];
    *(uint4*)&xs[r * 264 + (ch << 3)] = v;
  }
  __syncthreads();

  f32x4 acc[4][4];
#pragma unroll
  for (int i = 0; i < 4; ++i)
#pragma unroll
    for (int j = 0; j < 4; ++j) acc[i][j] = (f32x4){0.f, 0.f, 0.f, 0.f};

  unsigned short* ls = smemB + (w << 11);                       // wave-private 4KB (uniform)
  const unsigned short* gsb = Wsw + (w << 11) + (lane << 3);    // per-lane global src

  for (int kc = 0; kc < 8; ++kc)
#pragma unroll
    for (int t = 0; t < 3; ++t) {
      const unsigned short* gs = gsb + ((kc * 3 + t) << 13);
      // prior ds_reads of this buffer must be complete before overwrite
      asm volatile("s_waitcnt lgkmcnt(0)" ::: "memory");
      gload_lds16(gs, ls);
      gload_lds16(gs + 512, ls + 512);
      gload_lds16(gs + 1024, ls + 1024);
      gload_lds16(gs + 1536, ls + 1536);
      asm volatile("s_waitcnt vmcnt(0)" ::: "memory");
      __builtin_amdgcn_sched_barrier(0);
      bf16x8 af[4];
#pragma unroll
      for (int mt = 0; mt < 4; ++mt)
        af[mt] = *(const bf16x8*)&xs[(mt * 16 + c + t) * 264 + (kc << 5) + (g << 3)];
#pragma unroll
      for (int nt = 0; nt < 4; ++nt) {
        bf16x8 bfv = *(const bf16x8*)&smemB[((w << 2) + nt) * 512 + (lane << 3)];
#pragma unroll
        for (int mt = 0; mt < 4; ++mt)
          acc[mt][nt] = __builtin_amdgcn_mfma_f32_16x16x32_bf16(af[mt], bfv, acc[mt][nt], 0, 0, 0);
      }
    }
  __syncthreads();

  float pb[4];
#pragma unroll
  for (int nt = 0; nt < 4; ++nt) pb[nt] = bias[(w << 6) + nt * 16 + c];
#pragma unroll
  for (int mt = 0; mt < 4; ++mt)
#pragma unroll
    for (int r = 0; r < 4; ++r) {
      int row = mt * 16 + g * 4 + r;
#pragma unroll
      for (int nt = 0; nt < 4; ++nt) {
        float v = acc[mt][nt][r] + pb[nt];
        if (RELU) v = fmaxf(v, 0.f);
        swz[row * 264 + (w << 6) + nt * 16 + c] = f2bf(v);
      }
    }
  __syncthreads();
  if (!FRAGOUT) {
#pragma unroll
    for (int i = 0; i < 8; ++i) {
      int idx = tid + (i << 8);
      int row = idx >> 5, ch = idx & 31;
      *(uint4*)&outT[((rowbase + row) << 8) + (ch << 3)] = *(const uint4*)&swz[row * 264 + (ch << 3)];
    }
  } else {
    const int MT0 = (int)(rowbase >> 4);
#pragma unroll
    for (int i = 0; i < 8; ++i) {
      int f = tid + (i << 8);
      int mtl = f >> 9, kcl = (f >> 6) & 7, L = f & 63;
      int row = mtl * 16 + (L & 15), k0 = (kcl << 5) + ((L >> 4) << 3);
      uint4 v = *(const uint4*)&swz[row * 264 + k0];
      *(uint4*)&outT[(((size_t)(MT0 + mtl) * 8 + kcl) << 9) + L * 8] = v;
    }
  }
}

// ---------------- FULLY FUSED GEMM chain (restored Round-3 223us config) ----------------
// launch_bounds (256,4), LDS 40960 B. sdS/hS swizzled (conflict-free).
// Scalar coalesced epilogue with register-resident xp (8 vector loads).
__global__ __launch_bounds__(256, 4) void gemm_fused(
    const unsigned short* __restrict__ xp, const unsigned short* __restrict__ Bd,
    const unsigned short* __restrict__ B1, const unsigned short* __restrict__ B2,
    const float* __restrict__ lng, const float* __restrict__ lnb,
    const float* __restrict__ xin, float* __restrict__ outp) {
  __shared__ char smem[40960];
  unsigned short* sdS = (unsigned short*)smem;            // 32 KB: sd frag [4mt][8kc][512] (swizzled)
  unsigned short* hS = (unsigned short*)(smem + 32768);   // 8 KB: h chunk frag (swizzled)
  float* ps1 = (float*)(smem + 36864);                    // 1 KB (aliases hS; disjoint liveness)
  float* ps2 = (float*)(smem + 37888);                    // 1 KB
  unsigned short* swz = (unsigned short*)smem;            // epilogue alias [256][68] = 34816 B

  const int tid = threadIdx.x;
  const int w = tid >> 6;
  const int lane = tid & 63;
  const int g = lane >> 4, c = lane & 15;
  const int MT0 = blockIdx.x << 2;
  const int lsw8 = swz16(lane) * 8; // swizzled fragment-read offset (shorts)

  float pg[4], pb[4];
#pragma unroll
  for (int nt = 0; nt < 4; ++nt) {
    int col = (w << 6) + nt * 16 + c;
    pg[nt] = lng[col]; pb[nt] = lnb[col];
  }

  // ================= G0: freq = xp x Bd (K=256), then LN -> sdS =================
  {
    f32x4 a0[4][4];
#pragma unroll
    for (int i = 0; i < 4; ++i)
#pragma unroll
      for (int j = 0; j < 4; ++j) a0[i][j] = (f32x4){0.f, 0.f, 0.f, 0.f};

    for (int kc = 0; kc < 8; ++kc) {
      bf16x8 af[4];
#pragma unroll
      for (int mt = 0; mt < 4; ++mt)
        af[mt] = *(const bf16x8*)(xp + (((size_t)(MT0 + mt) << 3) + kc) * 512 + lane * 8);
#pragma unroll
      for (int nt = 0; nt < 4; ++nt) {
        bf16x8 bfv = *(const bf16x8*)(Bd + (((size_t)kc << 4) + (w << 2) + nt) * 512 + lane * 8);
#pragma unroll
        for (int mt = 0; mt < 4; ++mt)
          a0[mt][nt] = __builtin_amdgcn_mfma_f32_16x16x32_bf16(af[mt], bfv, a0[mt][nt], 0, 0, 0);
      }
    }

    // LN over 256 cols -> write sdS in swizzled frag layout
#pragma unroll
    for (int mt = 0; mt < 4; ++mt)
#pragma unroll
      for (int r = 0; r < 4; ++r) {
        float s1 = 0.f, s2 = 0.f;
#pragma unroll
        for (int nt = 0; nt < 4; ++nt) { float v = a0[mt][nt][r]; s1 += v; s2 += v * v; }
#pragma unroll
        for (int m = 1; m < 16; m <<= 1) { s1 += __shfl_xor(s1, m, 64); s2 += __shfl_xor(s2, m, 64); }
        if (c == 0) {
          ps1[(w << 6) + mt * 16 + g * 4 + r] = s1;
          ps2[(w << 6) + mt * 16 + g * 4 + r] = s2;
        }
      }
    __syncthreads();
#pragma unroll
    for (int mt = 0; mt < 4; ++mt)
#pragma unroll
      for (int r = 0; r < 4; ++r) {
        int row15 = g * 4 + r;
        int rr = mt * 16 + row15;
        float s1 = ps1[rr] + ps1[64 + rr] + ps1[128 + rr] + ps1[192 + rr];
        float s2 = ps2[rr] + ps2[64 + rr] + ps2[128 + rr] + ps2[192 + rr];
        float mu = s1 * (1.f / 256.f);
        float var = s2 * (1.f / 256.f) - mu * mu;
        float inv = __builtin_amdgcn_rsqf(var + 1e-6f);
#pragma unroll
        for (int nt = 0; nt < 4; ++nt) {
          int col = (w << 6) + nt * 16 + c;
          float v = (a0[mt][nt][r] - mu) * inv * pg[nt] + pb[nt];
          int blk = (((col >> 3) & 3) << 4) | row15;
          sdS[((mt << 3) + (col >> 5)) * 512 + swz16(blk) * 8 + (col & 7)] = f2bf(v);
        }
      }
    __syncthreads();
  }

  // ================= G1 (fc1+ReLU) chained into G2 (fc2 accumulation) =================
  f32x4 acc[4][4]; // fw accumulator (pre-sigmoid)
#pragma unroll
  for (int i = 0; i < 4; ++i)
#pragma unroll
    for (int j = 0; j < 4; ++j) acc[i][j] = (f32x4){0.f, 0.f, 0.f, 0.f};

  for (int hc = 0; hc < 8; ++hc) {
    // ---- G1 partial: h cols [hc*64, +64); wave w owns local cols w*16..+15
    f32x4 a1[4];
#pragma unroll
    for (int mt = 0; mt < 4; ++mt) a1[mt] = (f32x4){0.f, 0.f, 0.f, 0.f};
    const unsigned short* b1p = B1 + (size_t)((hc << 2) + w) * 512 + lane * 8;
    for (int kc = 0; kc < 8; ++kc) {
      bf16x8 bfv = *(const bf16x8*)(b1p + (size_t)kc * 16384);
#pragma unroll
      for (int mt = 0; mt < 4; ++mt) {
        bf16x8 af = *(const bf16x8*)&sdS[((mt << 3) + kc) * 512 + lsw8];
        a1[mt] = __builtin_amdgcn_mfma_f32_16x16x32_bf16(af, bfv, a1[mt], 0, 0, 0);
      }
    }
    // relu -> hS swizzled frag layout; klocal = w*16 + c
#pragma unroll
    for (int mt = 0; mt < 4; ++mt)
#pragma unroll
      for (int r = 0; r < 4; ++r) {
        int row15 = g * 4 + r;
        float v = fmaxf(a1[mt][r], 0.f);
        int blk = (((((w & 1) << 1) | (c >> 3))) << 4) | row15;
        hS[((mt << 1) + (w >> 1)) * 512 + swz16(blk) * 8 + (c & 7)] = f2bf(v);
      }
    __syncthreads();
    // ---- G2 partial: fw += h_chunk x fc2_chunk
#pragma unroll
    for (int kcl = 0; kcl < 2; ++kcl) {
      bf16x8 af2[4];
#pragma unroll
      for (int mt = 0; mt < 4; ++mt)
        af2[mt] = *(const bf16x8*)&hS[((mt << 1) + kcl) * 512 + lsw8];
#pragma unroll
      for (int nt = 0; nt < 4; ++nt) {
        bf16x8 bfv = *(const bf16x8*)(B2 + (size_t)((((hc << 1) + kcl) << 4) + (w << 2) + nt) * 512 +
                                      lane * 8);
#pragma unroll
        for (int mt = 0; mt < 4; ++mt)
          acc[mt][nt] = __builtin_amdgcn_mfma_f32_16x16x32_bf16(af2[mt], bfv, acc[mt][nt], 0, 0, 0);
      }
    }
    __syncthreads(); // before next chunk overwrites hS
  }

  // ================= sigmoid + LN + transposed scale/residual epilogue =================
#pragma unroll
  for (int mt = 0; mt < 4; ++mt)
#pragma unroll
    for (int nt = 0; nt < 4; ++nt)
#pragma unroll
      for (int r = 0; r < 4; ++r)
        acc[mt][nt][r] = __builtin_amdgcn_rcpf(1.f + __expf(-acc[mt][nt][r]));
#pragma unroll
  for (int mt = 0; mt < 4; ++mt)
#pragma unroll
    for (int r = 0; r < 4; ++r) {
      float s1 = 0.f, s2 = 0.f;
#pragma unroll
      for (int nt = 0; nt < 4; ++nt) { float v = acc[mt][nt][r]; s1 += v; s2 += v * v; }
#pragma unroll
      for (int m = 1; m < 16; m <<= 1) { s1 += __shfl_xor(s1, m, 64); s2 += __shfl_xor(s2, m, 64); }
      if (c == 0) {
        ps1[(w << 6) + mt * 16 + g * 4 + r] = s1;
        ps2[(w << 6) + mt * 16 + g * 4 + r] = s2;
      }
    }
  __syncthreads();
  float mu_[4][4], inv_[4][4];
#pragma unroll
  for (int mt = 0; mt < 4; ++mt)
#pragma unroll
    for (int r = 0; r < 4; ++r) {
      int rr = mt * 16 + g * 4 + r;
      float s1 = ps1[rr] + ps1[64 + rr] + ps1[128 + rr] + ps1[192 + rr];
      float s2 = ps2[rr] + ps2[64 + rr] + ps2[128 + rr] + ps2[192 + rr];
      float mu = s1 * (1.f / 256.f);
      float var = s2 * (1.f / 256.f) - mu * mu;
      mu_[mt][r] = mu;
      inv_[mt][r] = __builtin_amdgcn_rsqf(var + 1e-6f);
    }
#pragma unroll
  for (int mt = 0; mt < 4; ++mt)
#pragma unroll
    for (int nt = 0; nt < 4; ++nt) {
      alignas(8) unsigned short tmp[4];
#pragma unroll
      for (int r = 0; r < 4; ++r)
        tmp[r] = f2bf((acc[mt][nt][r] - mu_[mt][r]) * inv_[mt][r] * pg[nt] + pb[nt]);
      int col = (w << 6) + nt * 16 + c;
      *(uint2*)&swz[col * 68 + mt * 16 + g * 4] = *(const uint2*)tmp;
    }
  __syncthreads();
  {
    const int row0 = MT0 << 4;
    const int b = row0 >> 12;
    const int l0 = row0 & 4095;
    const int li = tid & 63, cq = tid >> 6;
    const size_t xbase = (size_t)(MT0 + (li >> 4)) * 4096 + (size_t)(li & 15) * 8;
    const size_t obase = ((size_t)((b << 8) + (cq << 6))) * LL + l0 + li;
#pragma unroll
    for (int i8 = 0; i8 < 8; ++i8) {
      bf16x8 xq = *(const bf16x8*)&xp[xbase + (size_t)((cq << 1) + (i8 >> 2)) * 512 +
                                      (size_t)(i8 & 3) * 128];
#pragma unroll
      for (int j = 0; j < 8; ++j) {
        int ic = (i8 << 3) + j;
        int ccol = (cq << 6) + ic;
        float fwv = bf2f(swz[ccol * 68 + li]);
        float xpv = bf2f((unsigned short)xq[j]);
        size_t o = obase + (size_t)ic * LL;
        float ov = fmaf(xpv, fwv, xin[o]);
        outp[o] = fmaxf(ov, 0.f);
      }
    }
  }
}

extern "C" void kernel_launch(void* const* d_in, const int* in_sizes, int n_in,
                              void* d_out, int out_size, void* d_ws, size_t ws_size,
                              hipStream_t stream) {
  const float* x    = (const float*)d_in[0];
  const float* w1   = (const float*)d_in[1];
  const float* g1   = (const float*)d_in[2];
  const float* b1   = (const float*)d_in[3];
  const float* m1   = (const float*)d_in[4];
  const float* v1   = (const float*)d_in[5];
  const float* w2   = (const float*)d_in[6];
  const float* g2   = (const float*)d_in[7];
  const float* b2   = (const float*)d_in[8];
  const float* m2   = (const float*)d_in[9];
  const float* v2   = (const float*)d_in[10];
  const float* fc1  = (const float*)d_in[11];
  const float* fc2  = (const float*)d_in[12];
  const float* lng  = (const float*)d_in[13];
  const float* lnb  = (const float*)d_in[14];
  float* out = (float*)d_out;

  float* ws = (float*)d_ws;
  float* b1f = ws;                                        // 256
  float* b2f = ws + 256;                                  // 256
  unsigned short* Bd   = (unsigned short*)(ws + 512);     // 65536 bf16
  unsigned short* B1   = (unsigned short*)(ws + 33280);   // 131072 bf16
  unsigned short* B2   = (unsigned short*)(ws + 98816);   // 131072 bf16
  unsigned short* W1sw = (unsigned short*)(ws + 164352);  // 196608 bf16
  unsigned short* W2sw = (unsigned short*)(ws + 262656);  // 196608 bf16
  unsigned short* xT    = (unsigned short*)(ws + 360960);    // 33554432 bf16
  unsigned short* y1T  = (unsigned short*)(ws + 17138176);   // 33554432 bf16
  unsigned short* xp_sw = (unsigned short*)(ws + 50692608);  // 33554432 bf16
  // total 67469824 floats = 269.9 MB

  init_bias<<<1, 256, 0, stream>>>(g1, b1, m1, v1, g2, b2, m2, v2, b1f, b2f);
  init_wsw<<<1536, 256, 0, stream>>>(w1, g1, v1, w2, g2, v2, W1sw, W2sw);
  init_bsw<<<1280, 256, 0, stream>>>(fc1, fc2, Bd, B1, B2);

  transpose_x<<<dim3(64, 4, 32), 256, 0, stream>>>(x, xT);

  conv_mfma<true, false><<<dim3(64, 32), 256, 0, stream>>>(xT, W1sw, b1f, y1T);
  conv_mfma<false, true><<<dim3(64, 32), 256, 0, stream>>>(y1T, W2sw, b2f, xp_sw);

  gemm_fused<<<2048, 256, 0, stream>>>(xp_sw, Bd, B1, B2, lng, lnb, x, out);
}

// Round 7
// 584.360 us; speedup vs baseline: 1.2192x; 1.0033x over previous
//
#include <hip/hip_runtime.h>
#include <math.h>

#define BB 32
#define CC 256
#define LL 4096

typedef __attribute__((ext_vector_type(8))) short bf16x8;
typedef __attribute__((ext_vector_type(4))) float f32x4;

__device__ __forceinline__ unsigned short f2bf(float f) {
  unsigned u = __float_as_uint(f);
  u = (u + 0x7FFFu + ((u >> 16) & 1u)) >> 16;
  return (unsigned short)u;
}
__device__ __forceinline__ float bf2f(unsigned short v) {
  return __uint_as_float(((unsigned)v) << 16);
}
// XOR-swizzle of a 16B-block index within a 1KB chunk (applied on both store & load)
__device__ __forceinline__ int swz16(int blk) { return blk ^ ((blk >> 3) & 7); }

// async global->LDS, 16B per lane; LDS dest = wave-uniform base + lane*16
__device__ __forceinline__ void gload_lds16(const unsigned short* g, unsigned short* l) {
  __builtin_amdgcn_global_load_lds(
      (const __attribute__((address_space(1))) unsigned int*)g,
      (__attribute__((address_space(3))) unsigned int*)l, 16, 0, 0);
}

// ---------------- init: biases (BN folded) ----------------
__global__ void init_bias(const float* __restrict__ g1, const float* __restrict__ b1,
                          const float* __restrict__ m1, const float* __restrict__ v1,
                          const float* __restrict__ g2, const float* __restrict__ b2,
                          const float* __restrict__ m2, const float* __restrict__ v2,
                          float* __restrict__ b1f, float* __restrict__ b2f) {
  int c = threadIdx.x;
  b1f[c] = b1[c] - m1[c] * g1[c] * rsqrtf(v1[c] + 1e-5f);
  b2f[c] = b2[c] - m2[c] * g2[c] * rsqrtf(v2[c] + 1e-5f);
}

// ---------------- init: conv weights, B-frag-linear bf16, BN-folded ----------------
__global__ void init_wsw(const float* __restrict__ w1, const float* __restrict__ g1,
                         const float* __restrict__ v1,
                         const float* __restrict__ w2, const float* __restrict__ g2,
                         const float* __restrict__ v2,
                         unsigned short* __restrict__ W1sw, unsigned short* __restrict__ W2sw) {
  int id = blockIdx.x * 256 + threadIdx.x; // 393216
  int cv = id / 196608;
  int i = id - cv * 196608;
  int kc3t = i >> 13;
  int kc = kc3t / 3, t = kc3t - 3 * kc;
  int rem = i & 8191;
  int nt = rem >> 9, L = (rem >> 3) & 63, j = i & 7;
  int co = nt * 16 + (L & 15);
  int ci = kc * 32 + ((L >> 4) << 3) + j;
  if (cv == 0) {
    float s = g1[co] * rsqrtf(v1[co] + 1e-5f);
    W1sw[i] = f2bf(w1[(co * 256 + ci) * 3 + t] * s);
  } else {
    float s = g2[co] * rsqrtf(v2[co] + 1e-5f);
    W2sw[i] = f2bf(w2[(co * 256 + ci) * 3 + t] * s);
  }
}

// ---------------- init: GEMM-chain B matrices, frag-linear bf16 ----------------
__global__ void init_bsw(const float* __restrict__ fc1, const float* __restrict__ fc2,
                         unsigned short* __restrict__ Bd, unsigned short* __restrict__ B1,
                         unsigned short* __restrict__ B2) {
  int id = blockIdx.x * 256 + threadIdx.x; // 327680 total
  if (id < 65536) {
    int i = id;
    int kc = i >> 13, nt = (i >> 9) & 15, L = (i >> 3) & 63, j = i & 7;
    int n = nt * 16 + (L & 15), k = kc * 32 + (L >> 4) * 8 + j;
    int m = (n * (2 * k + 1)) & 1023;
    float v = 2.0f * cosf(3.14159265358979323846f * (float)m * (1.0f / 512.0f));
    Bd[i] = f2bf(v);
  } else if (id < 65536 + 131072) {
    int i = id - 65536;
    int kc = i >> 14, nt = (i >> 9) & 31, L = (i >> 3) & 63, j = i & 7;
    int n = nt * 16 + (L & 15), k = kc * 32 + (L >> 4) * 8 + j;
    B1[i] = f2bf(fc1[n * 256 + k]);
  } else {
    int i = id - 65536 - 131072;
    int kc = i >> 13, nt = (i >> 9) & 15, L = (i >> 3) & 63, j = i & 7;
    int n = nt * 16 + (L & 15), k = kc * 32 + (L >> 4) * 8 + j;
    B2[i] = f2bf(fc2[n * 512 + k]);
  }
}

// ---------------- transpose: x fp32 [b][ci][l] -> xT bf16 [b][l][ci] ----------------
__global__ __launch_bounds__(256) void transpose_x(const float* __restrict__ x,
                                                   unsigned short* __restrict__ xT) {
  __shared__ unsigned short ts[64][68];
  const int tid = threadIdx.x;
  const int b = blockIdx.z, ci0 = blockIdx.y << 6, l0 = blockIdx.x << 6;
#pragma unroll
  for (int p = 0; p < 4; ++p) {
    int cc = (p << 4) + (tid >> 4);
    int ll = (tid & 15) << 2;
    float4 v = *(const float4*)&x[((((size_t)b << 8) + ci0 + cc) << 12) + l0 + ll];
    ts[ll + 0][cc] = f2bf(v.x);
    ts[ll + 1][cc] = f2bf(v.y);
    ts[ll + 2][cc] = f2bf(v.z);
    ts[ll + 3][cc] = f2bf(v.w);
  }
  __syncthreads();
#pragma unroll
  for (int p = 0; p < 4; ++p) {
    int idx = tid + (p << 8);
    int row = idx >> 4, ch = idx & 15;
    uint2 v = *(const uint2*)&ts[row][ch << 2];
    *(uint2*)&xT[((((size_t)b << 12) + l0 + row) << 8) + ci0 + (ch << 2)] = v;
  }
}

// ---------------- conv1 as implicit GEMM (MFMA bf16 16x16x32) ----------------
// r6 form: wave-private W staging + per-wave waitcnt, no K-loop barriers.
template <bool RELU>
__global__ __launch_bounds__(256, 3) void conv_mfma(
    const unsigned short* __restrict__ inT, const unsigned short* __restrict__ Wsw,
    const float* __restrict__ bias, unsigned short* __restrict__ outT) {
  __shared__ char smem[51232];
  unsigned short* xs = (unsigned short*)smem;              // [66][264]
  unsigned short* smemB = (unsigned short*)(smem + 34848); // 16 KB = 4 waves x 4KB private
  unsigned short* swz = (unsigned short*)smem;             // epilogue alias [64][264]

  const int tid = threadIdx.x;
  const int w = tid >> 6, lane = tid & 63;
  const int g = lane >> 4, c = lane & 15;
  const int l0 = blockIdx.x << 6;
  const int b = blockIdx.y;
  const size_t rowbase = ((size_t)b << 12) + l0;

  for (int idx = tid; idx < 66 * 32; idx += 256) {
    int r = idx >> 5, ch = idx & 31;
    int gl = l0 - 1 + r;
    uint4 v = {0, 0, 0, 0};
    if (gl >= 0 && gl < LL)
      v = *(const uint4*)&inT[((((size_t)b << 12) + gl) << 8) + (ch << 3)];
    *(uint4*)&xs[r * 264 + (ch << 3)] = v;
  }
  __syncthreads();

  f32x4 acc[4][4];
#pragma unroll
  for (int i = 0; i < 4; ++i)
#pragma unroll
    for (int j = 0; j < 4; ++j) acc[i][j] = (f32x4){0.f, 0.f, 0.f, 0.f};

  unsigned short* ls = smemB + (w << 11);
  const unsigned short* gsb = Wsw + (w << 11) + (lane << 3);

  for (int kc = 0; kc < 8; ++kc)
#pragma unroll
    for (int t = 0; t < 3; ++t) {
      const unsigned short* gs = gsb + ((kc * 3 + t) << 13);
      asm volatile("s_waitcnt lgkmcnt(0)" ::: "memory");
      gload_lds16(gs, ls);
      gload_lds16(gs + 512, ls + 512);
      gload_lds16(gs + 1024, ls + 1024);
      gload_lds16(gs + 1536, ls + 1536);
      asm volatile("s_waitcnt vmcnt(0)" ::: "memory");
      __builtin_amdgcn_sched_barrier(0);
      bf16x8 af[4];
#pragma unroll
      for (int mt = 0; mt < 4; ++mt)
        af[mt] = *(const bf16x8*)&xs[(mt * 16 + c + t) * 264 + (kc << 5) + (g << 3)];
#pragma unroll
      for (int nt = 0; nt < 4; ++nt) {
        bf16x8 bfv = *(const bf16x8*)&smemB[((w << 2) + nt) * 512 + (lane << 3)];
#pragma unroll
        for (int mt = 0; mt < 4; ++mt)
          acc[mt][nt] = __builtin_amdgcn_mfma_f32_16x16x32_bf16(af[mt], bfv, acc[mt][nt], 0, 0, 0);
      }
    }
  __syncthreads();

  float pb[4];
#pragma unroll
  for (int nt = 0; nt < 4; ++nt) pb[nt] = bias[(w << 6) + nt * 16 + c];
#pragma unroll
  for (int mt = 0; mt < 4; ++mt)
#pragma unroll
    for (int r = 0; r < 4; ++r) {
      int row = mt * 16 + g * 4 + r;
#pragma unroll
      for (int nt = 0; nt < 4; ++nt) {
        float v = acc[mt][nt][r] + pb[nt];
        if (RELU) v = fmaxf(v, 0.f);
        swz[row * 264 + (w << 6) + nt * 16 + c] = f2bf(v);
      }
    }
  __syncthreads();
#pragma unroll
  for (int i = 0; i < 8; ++i) {
    int idx = tid + (i << 8);
    int row = idx >> 5, ch = idx & 31;
    *(uint4*)&outT[((rowbase + row) << 8) + (ch << 3)] = *(const uint4*)&swz[row * 264 + (ch << 3)];
  }
}

// ---------------- conv2 + FULL GEMM chain, fused ----------------
// Phase A: conv2 (y1T staged, wave-private W2 staging) -> xp tile in LDS (frag+swz16).
// Epilogue xp fragments grabbed to registers before G0. sdS overwrites xpS after G0.
// LDS regions: [0,34848) xs -> xpS -> sdS -> swz ; [34848,51232) smemB -> hS+ps1+ps2.
__global__ __launch_bounds__(256, 3) void conv2_gemm(
    const unsigned short* __restrict__ y1T, const unsigned short* __restrict__ W2sw,
    const float* __restrict__ b2f,
    const unsigned short* __restrict__ Bd, const unsigned short* __restrict__ B1,
    const unsigned short* __restrict__ B2,
    const float* __restrict__ lng, const float* __restrict__ lnb,
    const float* __restrict__ xin, float* __restrict__ outp) {
  __shared__ char smem[51232];
  unsigned short* xs = (unsigned short*)smem;               // [66][264] (phase A)
  unsigned short* xpS = (unsigned short*)smem;              // 32 KB frag (over xs)
  unsigned short* sdS = (unsigned short*)smem;              // 32 KB frag (over xpS)
  unsigned short* swz = (unsigned short*)smem;              // [256][68] (final)
  unsigned short* smemB = (unsigned short*)(smem + 34848);  // 16 KB wave-private W2
  unsigned short* hS = (unsigned short*)(smem + 34848);     // 8 KB (over smemB)
  float* ps1 = (float*)(smem + 43040);                      // 1 KB
  float* ps2 = (float*)(smem + 44064);                      // 1 KB

  const int tid = threadIdx.x;
  const int w = tid >> 6;
  const int lane = tid & 63;
  const int g = lane >> 4, c = lane & 15;
  const int MT0 = blockIdx.x << 2;
  const int b = blockIdx.x >> 6;
  const int l0 = (blockIdx.x & 63) << 6;
  const int lsw8 = swz16(lane) * 8;

  // ================= Phase A: conv2 =================
  {
    for (int idx = tid; idx < 66 * 32; idx += 256) {
      int r = idx >> 5, ch = idx & 31;
      int gl = l0 - 1 + r;
      uint4 v = {0, 0, 0, 0};
      if (gl >= 0 && gl < LL)
        v = *(const uint4*)&y1T[((((size_t)b << 12) + gl) << 8) + (ch << 3)];
      *(uint4*)&xs[r * 264 + (ch << 3)] = v;
    }
    __syncthreads();

    f32x4 acc[4][4];
#pragma unroll
    for (int i = 0; i < 4; ++i)
#pragma unroll
      for (int j = 0; j < 4; ++j) acc[i][j] = (f32x4){0.f, 0.f, 0.f, 0.f};

    unsigned short* ls = smemB + (w << 11);
    const unsigned short* gsb = W2sw + (w << 11) + (lane << 3);

    for (int kc = 0; kc < 8; ++kc)
#pragma unroll
      for (int t = 0; t < 3; ++t) {
        const unsigned short* gs = gsb + ((kc * 3 + t) << 13);
        asm volatile("s_waitcnt lgkmcnt(0)" ::: "memory");
        gload_lds16(gs, ls);
        gload_lds16(gs + 512, ls + 512);
        gload_lds16(gs + 1024, ls + 1024);
        gload_lds16(gs + 1536, ls + 1536);
        asm volatile("s_waitcnt vmcnt(0)" ::: "memory");
        __builtin_amdgcn_sched_barrier(0);
        bf16x8 af[4];
#pragma unroll
        for (int mt = 0; mt < 4; ++mt)
          af[mt] = *(const bf16x8*)&xs[(mt * 16 + c + t) * 264 + (kc << 5) + (g << 3)];
#pragma unroll
        for (int nt = 0; nt < 4; ++nt) {
          bf16x8 bfv = *(const bf16x8*)&smemB[((w << 2) + nt) * 512 + (lane << 3)];
#pragma unroll
          for (int mt = 0; mt < 4; ++mt)
            acc[mt][nt] = __builtin_amdgcn_mfma_f32_16x16x32_bf16(af[mt], bfv, acc[mt][nt], 0, 0, 0);
        }
      }
    __syncthreads(); // all xs reads done before xpS overwrite

    float pbc[4];
#pragma unroll
    for (int nt = 0; nt < 4; ++nt) pbc[nt] = b2f[(w << 6) + nt * 16 + c];
#pragma unroll
    for (int mt = 0; mt < 4; ++mt)
#pragma unroll
      for (int r = 0; r < 4; ++r) {
        int row15 = g * 4 + r;
#pragma unroll
        for (int nt = 0; nt < 4; ++nt) {
          int col = (w << 6) + nt * 16 + c;
          float v = acc[mt][nt][r] + pbc[nt];
          int blk = (((col >> 3) & 3) << 4) | row15;
          xpS[((mt << 3) + (col >> 5)) * 512 + swz16(blk) * 8 + (col & 7)] = f2bf(v);
        }
      }
    __syncthreads();
  }

  // grab epilogue xp fragments into registers (xpS dies after G0)
  bf16x8 xqr[8];
  {
    const int li = tid & 63, cq = tid >> 6;
    const int mt_ = li >> 4;
#pragma unroll
    for (int i8 = 0; i8 < 8; ++i8) {
      int kcp = (cq << 1) + (i8 >> 2);
      int blk = ((i8 & 3) << 4) | (li & 15);
      xqr[i8] = *(const bf16x8*)&xpS[((mt_ << 3) + kcp) * 512 + swz16(blk) * 8];
    }
  }

  float pg[4], pb[4];
#pragma unroll
  for (int nt = 0; nt < 4; ++nt) {
    int col = (w << 6) + nt * 16 + c;
    pg[nt] = lng[col]; pb[nt] = lnb[col];
  }

  // ================= G0: freq = xp x Bd (K=256), then LN -> sdS =================
  {
    f32x4 a0[4][4];
#pragma unroll
    for (int i = 0; i < 4; ++i)
#pragma unroll
      for (int j = 0; j < 4; ++j) a0[i][j] = (f32x4){0.f, 0.f, 0.f, 0.f};

    for (int kc = 0; kc < 8; ++kc) {
      bf16x8 af[4];
#pragma unroll
      for (int mt = 0; mt < 4; ++mt)
        af[mt] = *(const bf16x8*)&xpS[((mt << 3) + kc) * 512 + lsw8];
#pragma unroll
      for (int nt = 0; nt < 4; ++nt) {
        bf16x8 bfv = *(const bf16x8*)(Bd + (((size_t)kc << 4) + (w << 2) + nt) * 512 + lane * 8);
#pragma unroll
        for (int mt = 0; mt < 4; ++mt)
          a0[mt][nt] = __builtin_amdgcn_mfma_f32_16x16x32_bf16(af[mt], bfv, a0[mt][nt], 0, 0, 0);
      }
    }

#pragma unroll
    for (int mt = 0; mt < 4; ++mt)
#pragma unroll
      for (int r = 0; r < 4; ++r) {
        float s1 = 0.f, s2 = 0.f;
#pragma unroll
        for (int nt = 0; nt < 4; ++nt) { float v = a0[mt][nt][r]; s1 += v; s2 += v * v; }
#pragma unroll
        for (int m = 1; m < 16; m <<= 1) { s1 += __shfl_xor(s1, m, 64); s2 += __shfl_xor(s2, m, 64); }
        if (c == 0) {
          ps1[(w << 6) + mt * 16 + g * 4 + r] = s1;
          ps2[(w << 6) + mt * 16 + g * 4 + r] = s2;
        }
      }
    __syncthreads(); // also separates xpS reads from sdS writes
#pragma unroll
    for (int mt = 0; mt < 4; ++mt)
#pragma unroll
      for (int r = 0; r < 4; ++r) {
        int row15 = g * 4 + r;
        int rr = mt * 16 + row15;
        float s1 = ps1[rr] + ps1[64 + rr] + ps1[128 + rr] + ps1[192 + rr];
        float s2 = ps2[rr] + ps2[64 + rr] + ps2[128 + rr] + ps2[192 + rr];
        float mu = s1 * (1.f / 256.f);
        float var = s2 * (1.f / 256.f) - mu * mu;
        float inv = __builtin_amdgcn_rsqf(var + 1e-6f);
#pragma unroll
        for (int nt = 0; nt < 4; ++nt) {
          int col = (w << 6) + nt * 16 + c;
          float v = (a0[mt][nt][r] - mu) * inv * pg[nt] + pb[nt];
          int blk = (((col >> 3) & 3) << 4) | row15;
          sdS[((mt << 3) + (col >> 5)) * 512 + swz16(blk) * 8 + (col & 7)] = f2bf(v);
        }
      }
    __syncthreads();
  }

  // ================= G1 (fc1+ReLU) chained into G2 (fc2 accumulation) =================
  f32x4 acc[4][4];
#pragma unroll
  for (int i = 0; i < 4; ++i)
#pragma unroll
    for (int j = 0; j < 4; ++j) acc[i][j] = (f32x4){0.f, 0.f, 0.f, 0.f};

  for (int hc = 0; hc < 8; ++hc) {
    f32x4 a1[4];
#pragma unroll
    for (int mt = 0; mt < 4; ++mt) a1[mt] = (f32x4){0.f, 0.f, 0.f, 0.f};
    const unsigned short* b1p = B1 + (size_t)((hc << 2) + w) * 512 + lane * 8;
    for (int kc = 0; kc < 8; ++kc) {
      bf16x8 bfv = *(const bf16x8*)(b1p + (size_t)kc * 16384);
#pragma unroll
      for (int mt = 0; mt < 4; ++mt) {
        bf16x8 af = *(const bf16x8*)&sdS[((mt << 3) + kc) * 512 + lsw8];
        a1[mt] = __builtin_amdgcn_mfma_f32_16x16x32_bf16(af, bfv, a1[mt], 0, 0, 0);
      }
    }
#pragma unroll
    for (int mt = 0; mt < 4; ++mt)
#pragma unroll
      for (int r = 0; r < 4; ++r) {
        int row15 = g * 4 + r;
        float v = fmaxf(a1[mt][r], 0.f);
        int blk = (((((w & 1) << 1) | (c >> 3))) << 4) | row15;
        hS[((mt << 1) + (w >> 1)) * 512 + swz16(blk) * 8 + (c & 7)] = f2bf(v);
      }
    __syncthreads();
#pragma unroll
    for (int kcl = 0; kcl < 2; ++kcl) {
      bf16x8 af2[4];
#pragma unroll
      for (int mt = 0; mt < 4; ++mt)
        af2[mt] = *(const bf16x8*)&hS[((mt << 1) + kcl) * 512 + lsw8];
#pragma unroll
      for (int nt = 0; nt < 4; ++nt) {
        bf16x8 bfv = *(const bf16x8*)(B2 + (size_t)((((hc << 1) + kcl) << 4) + (w << 2) + nt) * 512 +
                                      lane * 8);
#pragma unroll
        for (int mt = 0; mt < 4; ++mt)
          acc[mt][nt] = __builtin_amdgcn_mfma_f32_16x16x32_bf16(af2[mt], bfv, acc[mt][nt], 0, 0, 0);
      }
    }
    __syncthreads();
  }

  // ================= sigmoid + LN -> swz =================
#pragma unroll
  for (int mt = 0; mt < 4; ++mt)
#pragma unroll
    for (int nt = 0; nt < 4; ++nt)
#pragma unroll
      for (int r = 0; r < 4; ++r)
        acc[mt][nt][r] = __builtin_amdgcn_rcpf(1.f + __expf(-acc[mt][nt][r]));
#pragma unroll
  for (int mt = 0; mt < 4; ++mt)
#pragma unroll
    for (int r = 0; r < 4; ++r) {
      float s1 = 0.f, s2 = 0.f;
#pragma unroll
      for (int nt = 0; nt < 4; ++nt) { float v = acc[mt][nt][r]; s1 += v; s2 += v * v; }
#pragma unroll
      for (int m = 1; m < 16; m <<= 1) { s1 += __shfl_xor(s1, m, 64); s2 += __shfl_xor(s2, m, 64); }
      if (c == 0) {
        ps1[(w << 6) + mt * 16 + g * 4 + r] = s1;
        ps2[(w << 6) + mt * 16 + g * 4 + r] = s2;
      }
    }
  __syncthreads();
  float mu_[4][4], inv_[4][4];
#pragma unroll
  for (int mt = 0; mt < 4; ++mt)
#pragma unroll
    for (int r = 0; r < 4; ++r) {
      int rr = mt * 16 + g * 4 + r;
      float s1 = ps1[rr] + ps1[64 + rr] + ps1[128 + rr] + ps1[192 + rr];
      float s2 = ps2[rr] + ps2[64 + rr] + ps2[128 + rr] + ps2[192 + rr];
      float mu = s1 * (1.f / 256.f);
      float var = s2 * (1.f / 256.f) - mu * mu;
      mu_[mt][r] = mu;
      inv_[mt][r] = __builtin_amdgcn_rsqf(var + 1e-6f);
    }
#pragma unroll
  for (int mt = 0; mt < 4; ++mt)
#pragma unroll
    for (int nt = 0; nt < 4; ++nt) {
      alignas(8) unsigned short tmp[4];
#pragma unroll
      for (int r = 0; r < 4; ++r)
        tmp[r] = f2bf((acc[mt][nt][r] - mu_[mt][r]) * inv_[mt][r] * pg[nt] + pb[nt]);
      int col = (w << 6) + nt * 16 + c;
      *(uint2*)&swz[col * 68 + mt * 16 + g * 4] = *(const uint2*)tmp;
    }
  __syncthreads();

  // ================= scale/residual epilogue (xp from registers) =================
  {
    const int li = tid & 63, cq = tid >> 6;
    const size_t obase = ((size_t)((b << 8) + (cq << 6))) * LL + l0 + li;
#pragma unroll
    for (int i8 = 0; i8 < 8; ++i8) {
      bf16x8 xq = xqr[i8];
#pragma unroll
      for (int j = 0; j < 8; ++j) {
        int ic = (i8 << 3) + j;
        int ccol = (cq << 6) + ic;
        float fwv = bf2f(swz[ccol * 68 + li]);
        float xpv = bf2f((unsigned short)xq[j]);
        size_t o = obase + (size_t)ic * LL;
        float ov = fmaf(xpv, fwv, xin[o]);
        outp[o] = fmaxf(ov, 0.f);
      }
    }
  }
}

extern "C" void kernel_launch(void* const* d_in, const int* in_sizes, int n_in,
                              void* d_out, int out_size, void* d_ws, size_t ws_size,
                              hipStream_t stream) {
  const float* x    = (const float*)d_in[0];
  const float* w1   = (const float*)d_in[1];
  const float* g1   = (const float*)d_in[2];
  const float* b1   = (const float*)d_in[3];
  const float* m1   = (const float*)d_in[4];
  const float* v1   = (const float*)d_in[5];
  const float* w2   = (const float*)d_in[6];
  const float* g2   = (const float*)d_in[7];
  const float* b2   = (const float*)d_in[8];
  const float* m2   = (const float*)d_in[9];
  const float* v2   = (const float*)d_in[10];
  const float* fc1  = (const float*)d_in[11];
  const float* fc2  = (const float*)d_in[12];
  const float* lng  = (const float*)d_in[13];
  const float* lnb  = (const float*)d_in[14];
  float* out = (float*)d_out;

  float* ws = (float*)d_ws;
  float* b1f = ws;                                        // 256
  float* b2f = ws + 256;                                  // 256
  unsigned short* Bd   = (unsigned short*)(ws + 512);     // 65536 bf16
  unsigned short* B1   = (unsigned short*)(ws + 33280);   // 131072 bf16
  unsigned short* B2   = (unsigned short*)(ws + 98816);   // 131072 bf16
  unsigned short* W1sw = (unsigned short*)(ws + 164352);  // 196608 bf16
  unsigned short* W2sw = (unsigned short*)(ws + 262656);  // 196608 bf16
  unsigned short* xT   = (unsigned short*)(ws + 360960);    // 33554432 bf16
  unsigned short* y1T  = (unsigned short*)(ws + 17138176);  // 33554432 bf16

  init_bias<<<1, 256, 0, stream>>>(g1, b1, m1, v1, g2, b2, m2, v2, b1f, b2f);
  init_wsw<<<1536, 256, 0, stream>>>(w1, g1, v1, w2, g2, v2, W1sw, W2sw);
  init_bsw<<<1280, 256, 0, stream>>>(fc1, fc2, Bd, B1, B2);

  transpose_x<<<dim3(64, 4, 32), 256, 0, stream>>>(x, xT);

  conv_mfma<true><<<dim3(64, 32), 256, 0, stream>>>(xT, W1sw, b1f, y1T);

  conv2_gemm<<<2048, 256, 0, stream>>>(y1T, W2sw, b2f, Bd, B1, B2, lng, lnb, x, out);
}